// Round 5
// baseline (138.948 us; speedup 1.0000x reference)
//
#include <hip/hip_runtime.h>
#include <hip/hip_bf16.h>

// SSL-HSIC on MI355X, round 5.
// N=8192, D=128, B=4096, M=2, GAMMA=3, SIGMA=1.
// Rows are L2-normalized => ||x||^2 == 1, K = exp(min(dot-1,0)).
// Round-4 lessons: inline fp32->bf16 of B and libcall exp2f made the kernel
// VALU-bound at 2 blocks/CU. Now: prep writes bf16 once; gram reads bf16
// for A (swizzled LDS) and B (global, k-step pipelined); epilogue uses raw
// v_exp_f32 (arg in [-2.9,0], no fixups needed); grid 1024 blocks -> 4/CU.
// Final reduction split: 16-block red1 + 1-block red2 (1-block final was
// serially pulling 512KB cross-XCD).

using bf16   = __bf16;
using bf16x8 = __attribute__((ext_vector_type(8))) __bf16;
using f32x4  = __attribute__((ext_vector_type(4))) float;

#define N_ROWS 8192
#define LOG2E 1.4426950408889634f

#if __has_builtin(__builtin_amdgcn_exp2f)
#define EXP2(x) __builtin_amdgcn_exp2f(x)
#else
#define EXP2(x) exp2f(x)
#endif

// ---------------------------------------------------------------- prep ----
// fp32 -> bf16 (RNE via cast), 8 elems/thread. grid 512 x 256.
__global__ __launch_bounds__(256) void prep_kernel(
    const float* __restrict__ feat, unsigned short* __restrict__ xb) {
  const int g = blockIdx.x * 256 + threadIdx.x;
  const float4 a = ((const float4*)feat)[g * 2];
  const float4 b = ((const float4*)feat)[g * 2 + 1];
  bf16x8 r;
  r[0] = (__bf16)a.x; r[1] = (__bf16)a.y; r[2] = (__bf16)a.z; r[3] = (__bf16)a.w;
  r[4] = (__bf16)b.x; r[5] = (__bf16)b.y; r[6] = (__bf16)b.z; r[7] = (__bf16)b.w;
  ((bf16x8*)xb)[g] = r;
}

// ---------------------------------------------------------------- gram ----
// grid (16 col-chunks, 64 row-blocks); block = 4 waves 2x2 over 128x128,
// 4 column tiles per block. A staged once in XOR-swizzled LDS; B streamed
// bf16 from global (L2-hot), one k-step ahead in registers.
__global__ __launch_bounds__(256, 2) void gram_kernel(
    const bf16* __restrict__ xb, float* __restrict__ rpart,
    float* __restrict__ bscal) {
  const int bjc = blockIdx.x, bi = blockIdx.y;
  const int tid = threadIdx.x, lane = tid & 63, w = tid >> 6;
  const int wr = w >> 1, wc = w & 1;
  const int l15 = lane & 15, l4 = lane >> 4;

  __shared__ char  lds_a[32768];   // 128 rows x 256B, XOR-swizzled
  __shared__ float rbuf[128];
  __shared__ float sS[4], sD[4], sP[4];

  // ---- stage A: bf16 global -> swizzled LDS (pure copy) ----
  {
    const int rowbase = bi * 128;
#pragma unroll
    for (int i = 0; i < 8; ++i) {
      const int c = tid + i * 256;        // 2048 chunks of 16B
      const int row = c >> 4, seg = c & 15;
      const bf16x8 v = *(const bf16x8*)(xb + (rowbase + row) * 128 + seg * 8);
      const int sw = ((row << 8) | (seg << 4)) ^ ((row & 7) << 4);
      *(bf16x8*)(lds_a + sw) = v;
    }
    if (tid < 128) rbuf[tid] = 0.f;
  }
  __syncthreads();

  float rsum[4][4] = {};
  float s2a = 0.f, s2b = 0.f, pdiag = 0.f, ppos = 0.f;

  // B pipeline: one k-step of 4 fragments in flight
  bf16x8 bn[4];
  {
    const int brow0 = (bjc * 4) * 128 + wc * 64;
#pragma unroll
    for (int f = 0; f < 4; ++f)
      bn[f] = *(const bf16x8*)(xb + (brow0 + f * 16 + l15) * 128 + l4 * 8);
  }

#pragma unroll
  for (int t = 0; t < 4; ++t) {
    const int bj = bjc * 4 + t;
    const int brow0 = bj * 128 + wc * 64;

    f32x4 acc[4][4];
#pragma unroll
    for (int fr = 0; fr < 4; ++fr)
#pragma unroll
      for (int fc = 0; fc < 4; ++fc)
#pragma unroll
        for (int e = 0; e < 4; ++e) acc[fr][fc][e] = -1.0f;

#pragma unroll
    for (int ks = 0; ks < 4; ++ks) {
      bf16x8 bb[4];
#pragma unroll
      for (int f = 0; f < 4; ++f) bb[f] = bn[f];

      if (ks < 3 || t < 3) {               // prefetch next k-step / next tile
        const int nks = (ks + 1) & 3;
        const int nbrow0 = (ks < 3) ? brow0 : brow0 + 128;
#pragma unroll
        for (int f = 0; f < 4; ++f)
          bn[f] = *(const bf16x8*)(xb + (nbrow0 + f * 16 + l15) * 128 +
                                   nks * 32 + l4 * 8);
      }

#pragma unroll
      for (int fr = 0; fr < 4; ++fr) {
        const int arow = wr * 64 + fr * 16 + l15;
        const int byte = (arow << 8) + ks * 64 + (l4 << 4);
        const bf16x8 a = *(const bf16x8*)(lds_a + (byte ^ ((arow & 7) << 4)));
#pragma unroll
        for (int fc = 0; fc < 4; ++fc)
          acc[fr][fc] = __builtin_amdgcn_mfma_f32_16x16x32_bf16(
              a, bb[fc], acc[fr][fc], 0, 0, 0);
      }
    }

    const int dt = bj - bi;
    const bool isd = (dt == 0);
    const bool isp = (dt == 32) | (dt == -32);

#pragma unroll
    for (int fr = 0; fr < 4; ++fr) {
#pragma unroll
      for (int fc = 0; fc < 4; ++fc) {
#pragma unroll
        for (int e = 0; e < 4; ++e) {
          const float me = fminf(acc[fr][fc][e], 0.f);  // dot-1, clamped
          const float K = EXP2(me * LOG2E);
          if (fc & 1) s2b = fmaf(K, K, s2b); else s2a = fmaf(K, K, s2a);
          rsum[fr][e] += K;
          if (isd | isp) {
            const int rr = wr * 64 + fr * 16 + l4 * 4 + e;
            const int cc = wc * 64 + fc * 16 + l15;
            const float hit = (rr == cc) ? K : 0.f;
            if (isd) pdiag += hit; else ppos += hit;
          }
        }
      }
    }
  }

  // ---- block-level reductions (LDS only) ----
#pragma unroll
  for (int fr = 0; fr < 4; ++fr) {
#pragma unroll
    for (int e = 0; e < 4; ++e) {
      float r = rsum[fr][e];
      r += __shfl_xor(r, 1);
      r += __shfl_xor(r, 2);
      r += __shfl_xor(r, 4);
      r += __shfl_xor(r, 8);
      if (l15 == 0) atomicAdd(&rbuf[wr * 64 + fr * 16 + l4 * 4 + e], r);
    }
  }
  float s2 = s2a + s2b;
#pragma unroll
  for (int m = 1; m < 64; m <<= 1) {
    s2 += __shfl_xor(s2, m);
    pdiag += __shfl_xor(pdiag, m);
    ppos += __shfl_xor(ppos, m);
  }
  if (lane == 0) { sS[w] = s2; sD[w] = pdiag; sP[w] = ppos; }
  __syncthreads();

  const int slot = bi * 16 + bjc;
  if (tid < 128) rpart[slot * 128 + tid] = rbuf[tid];
  if (tid == 0) {
    bscal[slot * 3 + 0] = sS[0] + sS[1] + sS[2] + sS[3];
    bscal[slot * 3 + 1] = sD[0] + sD[1] + sD[2] + sD[3];
    bscal[slot * 3 + 2] = sP[0] + sP[1] + sP[2] + sP[3];
  }
}

// ---------------------------------------------------------------- red1 ----
// 16 blocks: block b reduces rows [b*512,(b+1)*512) of v and its bscal slice
// into gpart[b][5] (doubles: T, V2, S2, DG, PS).
__global__ __launch_bounds__(256) void red1_kernel(
    const float* __restrict__ rpart, const float* __restrict__ bscal,
    double* __restrict__ gpart) {
  const int b = blockIdx.x, tid = threadIdx.x, lane = tid & 63, w = tid >> 6;
  double t = 0.0, v2 = 0.0, s2 = 0.0, dg = 0.0, ps = 0.0;
#pragma unroll
  for (int k = 0; k < 2; ++k) {
    const int row = b * 512 + k * 256 + tid;
    const int rb = row >> 7, r = row & 127;
    float s = 0.f;
#pragma unroll
    for (int c = 0; c < 16; ++c) s += rpart[(rb * 16 + c) * 128 + r];
    const double x = (double)s;
    t += x;
    v2 += x * x;
  }
  if (tid < 64) {
    const int i = b * 64 + tid;
    s2 = (double)bscal[i * 3 + 0];
    dg = (double)bscal[i * 3 + 1];
    ps = (double)bscal[i * 3 + 2];
  }
#pragma unroll
  for (int m = 1; m < 64; m <<= 1) {
    t += __shfl_xor(t, m);
    v2 += __shfl_xor(v2, m);
    s2 += __shfl_xor(s2, m);
    dg += __shfl_xor(dg, m);
    ps += __shfl_xor(ps, m);
  }
  __shared__ double sh[5][4];
  if (lane == 0) {
    sh[0][w] = t; sh[1][w] = v2; sh[2][w] = s2; sh[3][w] = dg; sh[4][w] = ps;
  }
  __syncthreads();
  if (tid == 0) {
    gpart[b * 5 + 0] = sh[0][0] + sh[0][1] + sh[0][2] + sh[0][3];
    gpart[b * 5 + 1] = sh[1][0] + sh[1][1] + sh[1][2] + sh[1][3];
    gpart[b * 5 + 2] = sh[2][0] + sh[2][1] + sh[2][2] + sh[2][3];
    gpart[b * 5 + 3] = sh[3][0] + sh[3][1] + sh[3][2] + sh[3][3];
    gpart[b * 5 + 4] = sh[4][0] + sh[4][1] + sh[4][2] + sh[4][3];
  }
}

// ---------------------------------------------------------------- red2 ----
__global__ __launch_bounds__(64) void red2_kernel(
    const double* __restrict__ gpart, float* __restrict__ out) {
  const int lane = threadIdx.x;
  double t = 0.0, v2 = 0.0, s2 = 0.0, dg = 0.0, ps = 0.0;
  if (lane < 16) {
    t  = gpart[lane * 5 + 0];
    v2 = gpart[lane * 5 + 1];
    s2 = gpart[lane * 5 + 2];
    dg = gpart[lane * 5 + 3];
    ps = gpart[lane * 5 + 4];
  }
#pragma unroll
  for (int m = 1; m < 16; m <<= 1) {
    t += __shfl_xor(t, m);
    v2 += __shfl_xor(v2, m);
    s2 += __shfl_xor(s2, m);
    dg += __shfl_xor(dg, m);
    ps += __shfl_xor(ps, m);
  }
  if (lane == 0) {
    const double Nd = 8192.0, Bd = 4096.0;
    const double hzz = (s2 - (2.0 / Nd) * v2 + (t * t) / (Nd * Nd)) / (Nd * Nd);
    const double neg = (t - dg) - ps;
    const double t1 = ps / 8192.0;       // B*M*(M-1)
    const double t2 = neg / 67108864.0;  // B^2*M^2
    const double hzy = (Bd / (Bd - 1.0)) * (t1 - t2 - 1.0);
    out[0] = (float)(-hzy + 3.0 * sqrt(fmax(hzz, 0.0)));
  }
}

// -------------------------------------------------------------- launch ----
extern "C" void kernel_launch(void* const* d_in, const int* in_sizes, int n_in,
                              void* d_out, int out_size, void* d_ws,
                              size_t ws_size, hipStream_t stream) {
  (void)in_sizes; (void)n_in; (void)out_size; (void)ws_size;
  const float* feat = (const float*)d_in[0];
  char* ws = (char*)d_ws;
  // ws: xb 2MB | rpart 512KB | bscal 12KB | gpart 640B
  unsigned short* xb = (unsigned short*)ws;
  float* rpart  = (float*)(ws + 2097152);
  float* bscal  = (float*)(ws + 2097152 + 524288);
  double* gpart = (double*)(ws + 2097152 + 524288 + 12288);
  float* out = (float*)d_out;

  prep_kernel<<<512, 256, 0, stream>>>(feat, xb);
  gram_kernel<<<dim3(16, 64), 256, 0, stream>>>((const bf16*)xb, rpart, bscal);
  red1_kernel<<<16, 256, 0, stream>>>(rpart, bscal, gpart);
  red2_kernel<<<1, 64, 0, stream>>>(gpart, out);
}